// Round 6
// baseline (809.459 us; speedup 1.0000x reference)
//
#include <hip/hip_runtime.h>
#include <float.h>
#include <math.h>

#define NQ 2048
#define NT 100000
#define DIM 512
#define KTOP 5
#define NCAND 16            // screening survivors per query (exact re-rank set)
#define QTILE 128
#define TTILE 128
#define NTPC 13             // t-tiles per chunk
#define NCH 64              // chunk id space; 8 chunks per XCD
#define TBLKS 782           // ceil(NT/128) -> valid 128-row t-tile blocks
#define QBLKS 16            // NQ/128
#define NSUB 3              // t-sub-blocks per chunk (tiles {5,4,4})
#define CV_TBLKS (TBLKS*16) // 12512 convert tasks for T
#define CV_XBLKS ((NQ/128)*16) // 256 convert tasks for x

typedef float f32x4 __attribute__((ext_vector_type(4)));
typedef short s16x8 __attribute__((ext_vector_type(8)));
typedef unsigned int u32;
typedef unsigned short u16;

__device__ __forceinline__ int tsub_start(int ts) { return (13 * ts + 2) / 3; }

__device__ __forceinline__ bool lt_pair(float v1, int i1, float v2, int i2) {
  return v1 < v2 || (v1 == v2 && i1 < i2);
}

// screening insert: plain < (no index tie-break; selection is value-level,
// final ordering is re-established by the exact re-rank)
__device__ __forceinline__ void ins5f(float* tv, int* tix, float sc, int idx) {
  if (sc < tv[4]) {
    tv[4] = sc; tix[4] = idx;
#pragma unroll
    for (int p = 4; p > 0; --p)
      if (tv[p] < tv[p - 1]) {
        float tf = tv[p]; tv[p] = tv[p - 1]; tv[p - 1] = tf;
        int tn = tix[p]; tix[p] = tix[p - 1]; tix[p - 1] = tn;
      }
  }
}

__device__ __forceinline__ void ins5(float* tv, int* tix, float sc, int idx) {
  if (lt_pair(sc, idx, tv[4], tix[4])) {
    tv[4] = sc; tix[4] = idx;
#pragma unroll
    for (int p = 4; p > 0; --p)
      if (lt_pair(tv[p], tix[p], tv[p - 1], tix[p - 1])) {
        float tf = tv[p]; tv[p] = tv[p - 1]; tv[p - 1] = tf;
        int tn = tix[p]; tix[p] = tix[p - 1]; tix[p - 1] = tn;
      }
  }
}

__device__ __forceinline__ void merge5(float* av, int* ai, const float* bv, const int* bi) {
  float nv[5]; int ni[5];
#pragma unroll
  for (int s = 0; s < 5; ++s) {
    if (lt_pair(av[s], ai[s], bv[4 - s], bi[4 - s])) { nv[s] = av[s]; ni[s] = ai[s]; }
    else { nv[s] = bv[4 - s]; ni[s] = bi[4 - s]; }
  }
#pragma unroll
  for (int a = 0; a < 5; ++a)
#pragma unroll
    for (int b = 0; b < 4 - a; ++b)
      if (lt_pair(nv[b + 1], ni[b + 1], nv[b], ni[b])) {
        float tf = nv[b]; nv[b] = nv[b + 1]; nv[b + 1] = tf;
        int tn = ni[b]; ni[b] = ni[b + 1]; ni[b + 1] = tn;
      }
#pragma unroll
  for (int s = 0; s < 5; ++s) { av[s] = nv[s]; ai[s] = ni[s]; }
}

// ---------------- convert: fp32 -> frag-major HI bf16 only (screening) -------
// Screening is single-product bf16: error on d2 ~ +-0.3 absolute vs typical
// order-stat gaps ~5 near the minimum -> exact re-rank of top-16 is safe.
__global__ __launch_bounds__(256) void convert_kernel(
    const float* __restrict__ x, const float* __restrict__ T,
    short* __restrict__ xhi, short* __restrict__ thi,
    float* __restrict__ t2, float* __restrict__ x2) {
  __shared__ short lh[4096];
  const int bid = blockIdx.x;
  const bool isT = bid < CV_TBLKS;
  const int task = isT ? bid : bid - CV_TBLKS;
  const int blk = task >> 4, kbi = task & 15;
  const float* src = isT ? T : x;
  short* dhi = isT ? thi : xhi;
  float* nrm = isT ? t2 : x2;
  const int nsrc = isT ? NT : NQ;

  const int t = threadIdx.x;
  const int rr = t >> 1, half = t & 1;
  const int grow = blk * 128 + rr;
  const int rs = grow < nsrc ? grow : nsrc - 1;
  const float* p = src + (size_t)rs * DIM + kbi * 32 + half * 16;
  f32x4 v[4];
#pragma unroll
  for (int i = 0; i < 4; ++i) v[i] = ((const f32x4*)p)[i];

  float ss = 0.f;
#pragma unroll
  for (int g = 0; g < 2; ++g) {
    s16x8 hv;
#pragma unroll
    for (int e = 0; e < 8; ++e) {
      int i = g * 8 + e;
      float f = v[i >> 2][i & 3];
      ss = fmaf(f, f, ss);
      u32 u = __builtin_bit_cast(u32, f);
      u32 r1 = u + 0x7FFFu + ((u >> 16) & 1u);        // RNE to bf16
      hv[e] = (short)(r1 >> 16);
    }
    // frag unit: tile = rr>>4, quad = half*2+g, m = rr&15
    int unit = (rr >> 4) * 64 + (half * 2 + g) * 16 + (rr & 15);
    *(s16x8*)(lh + unit * 8) = hv;
  }
  ss += __shfl_xor(ss, 1, 64);       // pair (t, t^1) share a row
  if (half == 0 && grow < nsrc) atomicAdd(nrm + grow, ss);

  __syncthreads();
  size_t obase = ((size_t)(blk * 16 + kbi)) * 4096 + t * 16;
  *(s16x8*)(dhi + obase)     = *(const s16x8*)(lh + t * 16);
  *(s16x8*)(dhi + obase + 8) = *(const s16x8*)(lh + t * 16 + 8);
}

// ---------------- stage 1: screening GEMM, LDS-staged fragments -------------
// R5 post-mortem: dur tracks BYTES ISSUED through the global-load path across
// R0/R3/R4/R5 (16KB/wave-kbi ~ 700-755us, 8KB ~ 377-388us), independent of
// dbuf/occupancy/epilogue -> L1/VMEM-port bound. Each fragment byte was loaded
// by TWO waves. Fix: stage each (tile,kbi) 16KB slice into LDS ONCE via
// global_load_lds (halves global-path bytes), waves ds_read_b128 from LDS
// (separate port). Slices are contiguous in the frag-major workspace ->
// linear wave-uniform-dest staging, no swizzle needed; consecutive-lane
// ds_read_b128 is the m97-proven conflict-free pattern. One __syncthreads per
// kbi (2-phase, static buffer parity). setprio dropped (lockstep = null).
__global__ __launch_bounds__(256, 2) void knn_mfma(
    const short* __restrict__ xhi, const short* __restrict__ thi,
    const float* __restrict__ t2g,
    float* __restrict__ pvals, u16* __restrict__ pidx16) {
  // 32 KB: stg[buf][unit]; units 0-511 = T-slice (A), 512-1023 = X-slice (B).
  // Reused after the tt loop for the 5 KB cross-wave merge scratch.
  __shared__ char smem[32768];
  s16x8 (*stg)[1024] = (s16x8 (*)[1024])smem;
  float* msv = (float*)smem;            // 128*5 floats = 2560 B
  int*   msi = (int*)(smem + 2560);     // 128*5 ints   = 2560 B

  const int tid = threadIdx.x;
  const int w = tid >> 6;
  const int l = tid & 63;
  const int bid = blockIdx.x;
  const u32 rest = (u32)bid >> 3;
  const int inner = (int)(rest % 48u);
  const int chunk = (bid & 7) + 8 * (int)(rest / 48u);
  const int qblk = inner & 15;
  const int tsub = inner >> 4;                 // 0..2
  const int tstart = tsub_start(tsub);
  const int tend = tsub_start(tsub + 1);
  const int q0 = qblk * QTILE;
  const int wr = (w >> 1) * 64;    // t-offset within tile
  const int wc = (w & 1) * 64;     // q-offset within tile
  const int arow = wr >> 4;        // T fragment row group
  const int bcol = wc >> 4;        // X fragment col group

  // wave w stages segs w*4..w*4+3 (1KB each): segs 0-7 = T slice, 8-15 = X.
  // global src is per-lane (+l*16B); LDS dest is wave-uniform (+lane*16 by HW).
#define STAGE_KBI(kbi, b) do {                                                \
    _Pragma("unroll")                                                         \
    for (int c = 0; c < 4; ++c) {                                             \
      int seg = w * 4 + c;                                                    \
      const short* gsrc = (seg < 8)                                           \
        ? thi + (((size_t)(bblk * 16 + (kbi))) << 12) + (seg << 9) + (l << 3) \
        : xhi + (((size_t)(qblk * 16 + (kbi))) << 12) + ((seg - 8) << 9) + (l << 3); \
      __builtin_amdgcn_global_load_lds(                                       \
          (const __attribute__((address_space(1))) unsigned int*)gsrc,        \
          (__attribute__((address_space(3))) unsigned int*)&stg[(b)][seg * 64], \
          16, 0, 0);                                                          \
    }                                                                         \
  } while (0)

#define READ_MFMA(b) do {                                                     \
    s16x8 ah[4], bh[4];                                                       \
    _Pragma("unroll")                                                         \
    for (int i = 0; i < 4; ++i) {                                             \
      ah[i] = stg[(b)][(arow + i) * 64 + l];                                  \
      bh[i] = stg[(b)][512 + (bcol + i) * 64 + l];                            \
    }                                                                         \
    _Pragma("unroll")                                                         \
    for (int j = 0; j < 4; ++j)                                               \
      _Pragma("unroll")                                                       \
      for (int i = 0; i < 4; ++i)                                             \
        acc[i][j] = __builtin_amdgcn_mfma_f32_16x16x32_bf16(ah[i], bh[j],     \
                                                            acc[i][j], 0, 0, 0); \
  } while (0)

  float tv4[4][KTOP]; int tix4[4][KTOP];   // per-jj (per-q) top-5, registers
#pragma unroll
  for (int jj = 0; jj < 4; ++jj)
#pragma unroll
    for (int s = 0; s < KTOP; ++s) { tv4[jj][s] = FLT_MAX; tix4[jj][s] = 0x7FFFFFFF; }

#pragma unroll 1
  for (int tt = tstart; tt < tend; ++tt) {
    const int bblk = chunk * NTPC + tt;
    if (bblk >= TBLKS) continue;   // uniform per block: partials stay FLT_MAX
    const int tbase = bblk * TTILE;
    f32x4 acc[4][4];
#pragma unroll
    for (int i = 0; i < 4; ++i)
#pragma unroll
      for (int j = 0; j < 4; ++j) acc[i][j] = (f32x4){0.f, 0.f, 0.f, 0.f};

    STAGE_KBI(0, 0);
    __syncthreads();               // drains vmcnt -> buf0 ready
#pragma unroll 1
    for (int ks = 0; ks < 8; ++ks) {
      const int k0 = ks * 2;
      STAGE_KBI(k0 + 1, 1);        // prefetch odd kbi while computing buf0
      READ_MFMA(0);
      __syncthreads();             // buf0 reads done + buf1 staged
      if (ks < 7) STAGE_KBI(k0 + 2, 0);
      READ_MFMA(1);
      __syncthreads();             // buf1 reads done + buf0 staged
    }

    // epilogue, native layout: lane owns q = wc+jj*16+(l&15); t varies by (i,r)
    const int tg0 = tbase + wr + ((l >> 4) << 2);
    float t2v[16];
#pragma unroll
    for (int i = 0; i < 4; ++i)
#pragma unroll
      for (int r = 0; r < 4; ++r) {
        int t = tg0 + i * 16 + r;
        float vv = t2g[t < NT ? t : NT - 1];
        t2v[i * 4 + r] = t < NT ? vv : FLT_MAX;   // FLT_MAX-2acc rounds to FLT_MAX
      }
#pragma unroll
    for (int jj = 0; jj < 4; ++jj)
#pragma unroll
      for (int i = 0; i < 4; ++i)
#pragma unroll
        for (int r = 0; r < 4; ++r) {
          float sc = fmaf(-2.f, acc[i][jj][r], t2v[i * 4 + r]);
          ins5f(tv4[jj], tix4[jj], sc, tg0 + i * 16 + r);
        }
  }
#undef STAGE_KBI
#undef READ_MFMA

  // merge the 4 lanes sharing (l&15, jj): butterfly xor 16, 32 (once per block)
#pragma unroll
  for (int jj = 0; jj < 4; ++jj)
#pragma unroll
    for (int d = 16; d <= 32; d <<= 1) {
      float ov[KTOP]; int oi[KTOP];
#pragma unroll
      for (int s = 0; s < KTOP; ++s) {
        ov[s] = __shfl_xor(tv4[jj][s], d, 64);
        oi[s] = __shfl_xor(tix4[jj][s], d, 64);
      }
      merge5(tv4[jj], tix4[jj], ov, oi);
    }

  // cross-wave: waves 2,3 (t-half 1) publish, waves 0,1 consume + write out.
  // smem reuse is safe: all stage-LDS reads completed before the final kbi
  // barrier; epilogue/butterfly touch only registers.
  const int blockBase = (chunk * NTPC + tstart) * TTILE;
  if ((w >> 1) && (l >> 4) == 0) {
#pragma unroll
    for (int jj = 0; jj < 4; ++jj) {
      int qr = wc + jj * 16 + l;
#pragma unroll
      for (int s = 0; s < KTOP; ++s) {
        msv[qr * 5 + s] = tv4[jj][s];
        msi[qr * 5 + s] = tix4[jj][s];
      }
    }
  }
  __syncthreads();
  if (!(w >> 1) && (l >> 4) == 0) {
#pragma unroll
    for (int jj = 0; jj < 4; ++jj) {
      int qr = wc + jj * 16 + l;
      float ov[KTOP]; int oi[KTOP];
#pragma unroll
      for (int s = 0; s < KTOP; ++s) { ov[s] = msv[qr * 5 + s]; oi[s] = msi[qr * 5 + s]; }
      merge5(tv4[jj], tix4[jj], ov, oi);
      int q = q0 + qr;
      // u16 local index: block covers <=5 tiles = 640 t's from blockBase.
      // FLT_MAX sentinels carry garbage offsets - value-masked, never selected.
      size_t base = ((size_t)q * (NCH * NSUB) + (chunk * NSUB + tsub)) * KTOP;
#pragma unroll
      for (int s = 0; s < KTOP; ++s) {
        pvals[base + s] = tv4[jj][s];
        pidx16[base + s] = (u16)(tix4[jj][s] - blockBase);
      }
    }
  }
}

// ---------------- merge16: 960 approx partials -> top-16 indices/query ------
// One wave per query. 16 rounds of global argmin via butterfly reduce; the
// owning lane masks the winner. All register arrays statically indexed.
__global__ __launch_bounds__(256) void knn_merge16(
    const float* __restrict__ pvals, const u16* __restrict__ pidx16,
    int* __restrict__ idx16g) {
  const int M = NCH * NSUB * KTOP;  // 960 = 64 lanes x 15
  int q = (blockIdx.x * 256 + threadIdx.x) >> 6;
  int l = threadIdx.x & 63;
  if (q >= NQ) return;
  float v[15]; int ix[15];
  size_t base = (size_t)q * M;
#pragma unroll
  for (int j = 0; j < 15; ++j) {
    int m = j * 64 + l;
    int slot = m / KTOP;                    // candidate slot = chunk*NSUB+tsub
    int ch = slot / NSUB, ts = slot % NSUB;
    int gb = (ch * NTPC + tsub_start(ts)) * TTILE;
    v[j] = pvals[base + m];
    ix[j] = gb + (int)pidx16[base + m];
  }
  int mywin = 0x7FFFFFFF;
#pragma unroll 1
  for (int r = 0; r < NCAND; ++r) {
    float bv = FLT_MAX; int bi = 0x7FFFFFFF;
#pragma unroll
    for (int j = 0; j < 15; ++j)
      if (lt_pair(v[j], ix[j], bv, bi)) { bv = v[j]; bi = ix[j]; }
#pragma unroll
    for (int d = 1; d < 64; d <<= 1) {
      float ov = __shfl_xor(bv, d, 64);
      int oi = __shfl_xor(bi, d, 64);
      if (lt_pair(ov, oi, bv, bi)) { bv = ov; bi = oi; }
    }
    if (l == r) mywin = bi;     // all lanes agree on bi; lane r records it
#pragma unroll
    for (int j = 0; j < 15; ++j)
      if (ix[j] == bi) v[j] = FLT_MAX;      // global idx unique -> safe mask
  }
  if (l < NCAND) idx16g[q * NCAND + l] = mywin;
}

// ---------------- rerank: exact fp32 d2 for 16 cands/query -> final top-5 ---
__global__ __launch_bounds__(256) void knn_rerank(
    const float* __restrict__ x, const float* __restrict__ T,
    const int* __restrict__ idx16g, const int* __restrict__ labels,
    float* __restrict__ out) {
  __shared__ float sd2[4 * NCAND];
  __shared__ int sti[4 * NCAND];
  const int w = threadIdx.x >> 6, l = threadIdx.x & 63;
  const int q = blockIdx.x * 4 + w;
  const int cand = l >> 2, sub = l & 3;
  const int ti = idx16g[q * NCAND + cand];
  const f32x4* tp = (const f32x4*)(T + (size_t)ti * DIM + sub * 128);
  const f32x4* xp = (const f32x4*)(x + (size_t)q * DIM + sub * 128);
  float dot = 0.f, tt = 0.f, xx = 0.f;
#pragma unroll
  for (int i = 0; i < 32; ++i) {
    f32x4 a = xp[i], b = tp[i];
#pragma unroll
    for (int c = 0; c < 4; ++c) {
      dot = fmaf(a[c], b[c], dot);
      tt  = fmaf(b[c], b[c], tt);
      xx  = fmaf(a[c], a[c], xx);
    }
  }
#pragma unroll
  for (int d = 1; d < 4; d <<= 1) {
    dot += __shfl_xor(dot, d, 64);
    tt  += __shfl_xor(tt, d, 64);
    xx  += __shfl_xor(xx, d, 64);
  }
  if (sub == 0) { sd2[w * NCAND + cand] = xx + tt - 2.f * dot; sti[w * NCAND + cand] = ti; }
  __syncthreads();
  if (l == 0) {
    float tv[KTOP]; int tix[KTOP];
#pragma unroll
    for (int s = 0; s < KTOP; ++s) { tv[s] = FLT_MAX; tix[s] = 0x7FFFFFFF; }
#pragma unroll
    for (int c = 0; c < NCAND; ++c) ins5(tv, tix, sd2[w * NCAND + c], sti[w * NCAND + c]);
#pragma unroll
    for (int s = 0; s < KTOP; ++s) {
      float d2 = tv[s] > 0.f ? tv[s] : 0.f;
      out[(size_t)q * KTOP + s] = sqrtf(d2);                          // topk_dists [Q,K]
      out[(size_t)NQ * KTOP + (size_t)q * KTOP + s] = (float)tix[s];  // topk_inds [Q,K]
      out[(size_t)2 * NQ * KTOP + (size_t)s * NQ + q] =
          (float)labels[tix[s]];                                       // pred [K,Q]
    }
  }
}

extern "C" void kernel_launch(void* const* d_in, const int* in_sizes, int n_in,
                              void* d_out, int out_size, void* d_ws, size_t ws_size,
                              hipStream_t stream) {
  const float* x = (const float*)d_in[0];
  const float* T = (const float*)d_in[1];
  const int* labels = (const int*)d_in[2];
  float* out = (float*)d_out;
  char* ws = (char*)d_ws;

  // ws layout (bytes), total ~116.9 MB
  float* t2     = (float*)(ws + 0);             // 400,000
  float* x2     = (float*)(ws + 401408);        // 8,192
  short* xhi    = (short*)(ws + 409600);        // 2,097,152
  short* thi    = (short*)(ws + 2506752);       // 102,498,304 (end 105,005,056)
  float* pvals  = (float*)(ws + 105005056);     // 7,864,320
  u16*   pidx16 = (u16*)(ws + 112869376);       // 3,932,160
  int*   idx16g = (int*)(ws + 116801536);       // 131,072 (end 116,932,608)

  hipMemsetAsync(ws, 0, 409600, stream);        // zero t2/x2 for atomic norms

  convert_kernel<<<CV_TBLKS + CV_XBLKS, 256, 0, stream>>>(
      x, T, xhi, thi, t2, x2);

  knn_mfma<<<QBLKS * NSUB * NCH, 256, 0, stream>>>(
      xhi, thi, t2, pvals, pidx16);

  knn_merge16<<<(NQ * 64 + 255) / 256, 256, 0, stream>>>(pvals, pidx16, idx16g);

  knn_rerank<<<NQ / 4, 256, 0, stream>>>(x, T, idx16g, labels, out);
}

// Round 7
// 762.110 us; speedup vs baseline: 1.0621x; 1.0621x over previous
//
#include <hip/hip_runtime.h>
#include <float.h>
#include <math.h>

#define NQ 2048
#define NT 100000
#define DIM 512
#define KTOP 5
#define NCAND 16            // screening survivors per query (exact re-rank set)
#define QTILE 128
#define TTILE 128
#define NTPC 13             // t-tiles per chunk
#define NCH 64              // chunk id space; 8 chunks per XCD
#define TBLKS 782           // ceil(NT/128) -> valid 128-row t-tile blocks
#define QBLKS 16            // NQ/128
#define NSUB 6              // t-sub-blocks per chunk (tiles {3,2,2,2,2,2})
#define CV_TBLKS (TBLKS*16) // 12512 convert tasks for T
#define CV_XBLKS ((NQ/128)*16) // 256 convert tasks for x

typedef float f32x4 __attribute__((ext_vector_type(4)));
typedef short s16x8 __attribute__((ext_vector_type(8)));
typedef unsigned int u32;
typedef unsigned short u16;

__device__ __forceinline__ int tsub_start(int ts) { return (13 * ts + 5) / 6; }

__device__ __forceinline__ bool lt_pair(float v1, int i1, float v2, int i2) {
  return v1 < v2 || (v1 == v2 && i1 < i2);
}

// screening insert: plain < (no index tie-break; selection is value-level,
// final ordering is re-established by the exact re-rank)
__device__ __forceinline__ void ins5f(float* tv, int* tix, float sc, int idx) {
  if (sc < tv[4]) {
    tv[4] = sc; tix[4] = idx;
#pragma unroll
    for (int p = 4; p > 0; --p)
      if (tv[p] < tv[p - 1]) {
        float tf = tv[p]; tv[p] = tv[p - 1]; tv[p - 1] = tf;
        int tn = tix[p]; tix[p] = tix[p - 1]; tix[p - 1] = tn;
      }
  }
}

__device__ __forceinline__ void ins5(float* tv, int* tix, float sc, int idx) {
  if (lt_pair(sc, idx, tv[4], tix[4])) {
    tv[4] = sc; tix[4] = idx;
#pragma unroll
    for (int p = 4; p > 0; --p)
      if (lt_pair(tv[p], tix[p], tv[p - 1], tix[p - 1])) {
        float tf = tv[p]; tv[p] = tv[p - 1]; tv[p - 1] = tf;
        int tn = tix[p]; tix[p] = tix[p - 1]; tix[p - 1] = tn;
      }
  }
}

__device__ __forceinline__ void merge5(float* av, int* ai, const float* bv, const int* bi) {
  float nv[5]; int ni[5];
#pragma unroll
  for (int s = 0; s < 5; ++s) {
    if (lt_pair(av[s], ai[s], bv[4 - s], bi[4 - s])) { nv[s] = av[s]; ni[s] = ai[s]; }
    else { nv[s] = bv[4 - s]; ni[s] = bi[4 - s]; }
  }
#pragma unroll
  for (int a = 0; a < 5; ++a)
#pragma unroll
    for (int b = 0; b < 4 - a; ++b)
      if (lt_pair(nv[b + 1], ni[b + 1], nv[b], ni[b])) {
        float tf = nv[b]; nv[b] = nv[b + 1]; nv[b + 1] = tf;
        int tn = ni[b]; ni[b] = ni[b + 1]; ni[b + 1] = tn;
      }
#pragma unroll
  for (int s = 0; s < 5; ++s) { av[s] = nv[s]; ai[s] = ni[s]; }
}

// ---------------- convert: fp32 -> frag-major HI bf16 only (screening) -------
// Screening is single-product bf16: error on d2 ~ +-0.3 absolute vs typical
// order-stat gaps ~5 near the minimum -> exact re-rank of top-16 is safe.
__global__ __launch_bounds__(256) void convert_kernel(
    const float* __restrict__ x, const float* __restrict__ T,
    short* __restrict__ xhi, short* __restrict__ thi,
    float* __restrict__ t2, float* __restrict__ x2) {
  __shared__ short lh[4096];
  const int bid = blockIdx.x;
  const bool isT = bid < CV_TBLKS;
  const int task = isT ? bid : bid - CV_TBLKS;
  const int blk = task >> 4, kbi = task & 15;
  const float* src = isT ? T : x;
  short* dhi = isT ? thi : xhi;
  float* nrm = isT ? t2 : x2;
  const int nsrc = isT ? NT : NQ;

  const int t = threadIdx.x;
  const int rr = t >> 1, half = t & 1;
  const int grow = blk * 128 + rr;
  const int rs = grow < nsrc ? grow : nsrc - 1;
  const float* p = src + (size_t)rs * DIM + kbi * 32 + half * 16;
  f32x4 v[4];
#pragma unroll
  for (int i = 0; i < 4; ++i) v[i] = ((const f32x4*)p)[i];

  float ss = 0.f;
#pragma unroll
  for (int g = 0; g < 2; ++g) {
    s16x8 hv;
#pragma unroll
    for (int e = 0; e < 8; ++e) {
      int i = g * 8 + e;
      float f = v[i >> 2][i & 3];
      ss = fmaf(f, f, ss);
      u32 u = __builtin_bit_cast(u32, f);
      u32 r1 = u + 0x7FFFu + ((u >> 16) & 1u);        // RNE to bf16
      hv[e] = (short)(r1 >> 16);
    }
    // frag unit: tile = rr>>4, quad = half*2+g, m = rr&15
    int unit = (rr >> 4) * 64 + (half * 2 + g) * 16 + (rr & 15);
    *(s16x8*)(lh + unit * 8) = hv;
  }
  ss += __shfl_xor(ss, 1, 64);       // pair (t, t^1) share a row
  if (half == 0 && grow < nsrc) atomicAdd(nrm + grow, ss);

  __syncthreads();
  size_t obase = ((size_t)(blk * 16 + kbi)) * 4096 + t * 16;
  *(s16x8*)(dhi + obase)     = *(const s16x8*)(lh + t * 16);
  *(s16x8*)(dhi + obase + 8) = *(const s16x8*)(lh + t * 16 + 8);
}

// ---------------- stage 1: screening GEMM, LDS-staged fragments -------------
// R5 post-mortem: direct-load variants all sit at ~17.6-19.6 TB/s through L2
// = ~90% of the per-XCD L2 delivery ceiling (~1KB/cyc/XCD) -> L2-BW bound.
// LDS staging (R6) halves L2 bytes: each (tile,kbi) 16KB slice staged ONCE via
// global_load_lds, waves ds_read_b128 from LDS. R6 regression root-cause: the
// 2-barrier loop's vmcnt(0) drain needs ~3 blocks/CU of wave-overlap to hide
// (m97 runs 12 waves/CU); (256,2) capped us at 8. Fix: (256,3) -- VGPR is 96,
// far under the ~170 cap (no R1-style spill risk); LDS 3x32KB=96 <= 160KB.
// NSUB=6 keeps one-chunk-per-XCD locality with 96 co-resident blocks/XCD.
__global__ __launch_bounds__(256, 3) void knn_mfma(
    const short* __restrict__ xhi, const short* __restrict__ thi,
    const float* __restrict__ t2g,
    float* __restrict__ pvals, u16* __restrict__ pidx16) {
  // 32 KB: stg[buf][unit]; units 0-511 = T-slice (A), 512-1023 = X-slice (B).
  // Reused after the tt loop for the 5 KB cross-wave merge scratch.
  __shared__ char smem[32768];
  s16x8 (*stg)[1024] = (s16x8 (*)[1024])smem;
  float* msv = (float*)smem;            // 128*5 floats = 2560 B
  int*   msi = (int*)(smem + 2560);     // 128*5 ints   = 2560 B

  const int tid = threadIdx.x;
  const int w = tid >> 6;
  const int l = tid & 63;
  const int bid = blockIdx.x;
  const u32 rest = (u32)bid >> 3;
  const int inner = (int)(rest % 96u);
  const int chunk = (bid & 7) + 8 * (int)(rest / 96u);
  const int qblk = inner & 15;
  const int tsub = inner >> 4;                 // 0..5
  const int tstart = tsub_start(tsub);
  const int tend = tsub_start(tsub + 1);
  const int q0 = qblk * QTILE;
  const int wr = (w >> 1) * 64;    // t-offset within tile
  const int wc = (w & 1) * 64;     // q-offset within tile
  const int arow = wr >> 4;        // T fragment row group
  const int bcol = wc >> 4;        // X fragment col group

  // wave w stages segs w*4..w*4+3 (1KB each): segs 0-7 = T slice, 8-15 = X.
  // global src is per-lane (+l*16B); LDS dest is wave-uniform (+lane*16 by HW).
#define STAGE_KBI(kbi, b) do {                                                \
    _Pragma("unroll")                                                         \
    for (int c = 0; c < 4; ++c) {                                             \
      int seg = w * 4 + c;                                                    \
      const short* gsrc = (seg < 8)                                           \
        ? thi + (((size_t)(bblk * 16 + (kbi))) << 12) + (seg << 9) + (l << 3) \
        : xhi + (((size_t)(qblk * 16 + (kbi))) << 12) + ((seg - 8) << 9) + (l << 3); \
      __builtin_amdgcn_global_load_lds(                                       \
          (const __attribute__((address_space(1))) unsigned int*)gsrc,        \
          (__attribute__((address_space(3))) unsigned int*)&stg[(b)][seg * 64], \
          16, 0, 0);                                                          \
    }                                                                         \
  } while (0)

#define READ_MFMA(b) do {                                                     \
    s16x8 ah[4], bh[4];                                                       \
    _Pragma("unroll")                                                         \
    for (int i = 0; i < 4; ++i) {                                             \
      ah[i] = stg[(b)][(arow + i) * 64 + l];                                  \
      bh[i] = stg[(b)][512 + (bcol + i) * 64 + l];                            \
    }                                                                         \
    _Pragma("unroll")                                                         \
    for (int j = 0; j < 4; ++j)                                               \
      _Pragma("unroll")                                                       \
      for (int i = 0; i < 4; ++i)                                             \
        acc[i][j] = __builtin_amdgcn_mfma_f32_16x16x32_bf16(ah[i], bh[j],     \
                                                            acc[i][j], 0, 0, 0); \
  } while (0)

  float tv4[4][KTOP]; int tix4[4][KTOP];   // per-jj (per-q) top-5, registers
#pragma unroll
  for (int jj = 0; jj < 4; ++jj)
#pragma unroll
    for (int s = 0; s < KTOP; ++s) { tv4[jj][s] = FLT_MAX; tix4[jj][s] = 0x7FFFFFFF; }

#pragma unroll 1
  for (int tt = tstart; tt < tend; ++tt) {
    const int bblk = chunk * NTPC + tt;
    if (bblk >= TBLKS) continue;   // uniform per block: partials stay FLT_MAX
    const int tbase = bblk * TTILE;
    f32x4 acc[4][4];
#pragma unroll
    for (int i = 0; i < 4; ++i)
#pragma unroll
      for (int j = 0; j < 4; ++j) acc[i][j] = (f32x4){0.f, 0.f, 0.f, 0.f};

    STAGE_KBI(0, 0);
    __syncthreads();               // drains vmcnt -> buf0 ready
#pragma unroll 1
    for (int ks = 0; ks < 8; ++ks) {
      const int k0 = ks * 2;
      STAGE_KBI(k0 + 1, 1);        // prefetch odd kbi while computing buf0
      READ_MFMA(0);
      __syncthreads();             // buf0 reads done + buf1 staged
      if (ks < 7) STAGE_KBI(k0 + 2, 0);
      READ_MFMA(1);
      __syncthreads();             // buf1 reads done + buf0 staged
    }

    // epilogue, native layout: lane owns q = wc+jj*16+(l&15); t varies by (i,r)
    const int tg0 = tbase + wr + ((l >> 4) << 2);
    float t2v[16];
#pragma unroll
    for (int i = 0; i < 4; ++i)
#pragma unroll
      for (int r = 0; r < 4; ++r) {
        int t = tg0 + i * 16 + r;
        float vv = t2g[t < NT ? t : NT - 1];
        t2v[i * 4 + r] = t < NT ? vv : FLT_MAX;   // FLT_MAX-2acc rounds to FLT_MAX
      }
#pragma unroll
    for (int jj = 0; jj < 4; ++jj)
#pragma unroll
      for (int i = 0; i < 4; ++i)
#pragma unroll
        for (int r = 0; r < 4; ++r) {
          float sc = fmaf(-2.f, acc[i][jj][r], t2v[i * 4 + r]);
          ins5f(tv4[jj], tix4[jj], sc, tg0 + i * 16 + r);
        }
  }
#undef STAGE_KBI
#undef READ_MFMA

  // merge the 4 lanes sharing (l&15, jj): butterfly xor 16, 32 (once per block)
#pragma unroll
  for (int jj = 0; jj < 4; ++jj)
#pragma unroll
    for (int d = 16; d <= 32; d <<= 1) {
      float ov[KTOP]; int oi[KTOP];
#pragma unroll
      for (int s = 0; s < KTOP; ++s) {
        ov[s] = __shfl_xor(tv4[jj][s], d, 64);
        oi[s] = __shfl_xor(tix4[jj][s], d, 64);
      }
      merge5(tv4[jj], tix4[jj], ov, oi);
    }

  // cross-wave: waves 2,3 (t-half 1) publish, waves 0,1 consume + write out.
  // smem reuse is safe: all stage-LDS reads completed before the final kbi
  // barrier; epilogue/butterfly touch only registers.
  const int blockBase = (chunk * NTPC + tstart) * TTILE;
  if ((w >> 1) && (l >> 4) == 0) {
#pragma unroll
    for (int jj = 0; jj < 4; ++jj) {
      int qr = wc + jj * 16 + l;
#pragma unroll
      for (int s = 0; s < KTOP; ++s) {
        msv[qr * 5 + s] = tv4[jj][s];
        msi[qr * 5 + s] = tix4[jj][s];
      }
    }
  }
  __syncthreads();
  if (!(w >> 1) && (l >> 4) == 0) {
#pragma unroll
    for (int jj = 0; jj < 4; ++jj) {
      int qr = wc + jj * 16 + l;
      float ov[KTOP]; int oi[KTOP];
#pragma unroll
      for (int s = 0; s < KTOP; ++s) { ov[s] = msv[qr * 5 + s]; oi[s] = msi[qr * 5 + s]; }
      merge5(tv4[jj], tix4[jj], ov, oi);
      int q = q0 + qr;
      // u16 local index: block covers <=3 tiles = 384 t's from blockBase.
      // FLT_MAX sentinels carry garbage offsets - value-masked, never selected.
      size_t base = ((size_t)q * (NCH * NSUB) + (chunk * NSUB + tsub)) * KTOP;
#pragma unroll
      for (int s = 0; s < KTOP; ++s) {
        pvals[base + s] = tv4[jj][s];
        pidx16[base + s] = (u16)(tix4[jj][s] - blockBase);
      }
    }
  }
}

// ---------------- merge16: 1920 approx partials -> top-16 indices/query -----
// One wave per query. 16 rounds of global argmin via butterfly reduce; the
// owning lane masks the winner. All register arrays statically indexed.
__global__ __launch_bounds__(256) void knn_merge16(
    const float* __restrict__ pvals, const u16* __restrict__ pidx16,
    int* __restrict__ idx16g) {
  const int M = NCH * NSUB * KTOP;  // 1920 = 64 lanes x 30
  int q = (blockIdx.x * 256 + threadIdx.x) >> 6;
  int l = threadIdx.x & 63;
  if (q >= NQ) return;
  float v[30]; int ix[30];
  size_t base = (size_t)q * M;
#pragma unroll
  for (int j = 0; j < 30; ++j) {
    int m = j * 64 + l;
    int slot = m / KTOP;                    // candidate slot = chunk*NSUB+tsub
    int ch = slot / NSUB, ts = slot % NSUB;
    int gb = (ch * NTPC + tsub_start(ts)) * TTILE;
    v[j] = pvals[base + m];
    ix[j] = gb + (int)pidx16[base + m];
  }
  int mywin = 0x7FFFFFFF;
#pragma unroll 1
  for (int r = 0; r < NCAND; ++r) {
    float bv = FLT_MAX; int bi = 0x7FFFFFFF;
#pragma unroll
    for (int j = 0; j < 30; ++j)
      if (lt_pair(v[j], ix[j], bv, bi)) { bv = v[j]; bi = ix[j]; }
#pragma unroll
    for (int d = 1; d < 64; d <<= 1) {
      float ov = __shfl_xor(bv, d, 64);
      int oi = __shfl_xor(bi, d, 64);
      if (lt_pair(ov, oi, bv, bi)) { bv = ov; bi = oi; }
    }
    if (l == r) mywin = bi;     // all lanes agree on bi; lane r records it
#pragma unroll
    for (int j = 0; j < 30; ++j)
      if (ix[j] == bi) v[j] = FLT_MAX;      // global idx unique -> safe mask
  }
  if (l < NCAND) idx16g[q * NCAND + l] = mywin;
}

// ---------------- rerank: exact fp32 d2 for 16 cands/query -> final top-5 ---
__global__ __launch_bounds__(256) void knn_rerank(
    const float* __restrict__ x, const float* __restrict__ T,
    const int* __restrict__ idx16g, const int* __restrict__ labels,
    float* __restrict__ out) {
  __shared__ float sd2[4 * NCAND];
  __shared__ int sti[4 * NCAND];
  const int w = threadIdx.x >> 6, l = threadIdx.x & 63;
  const int q = blockIdx.x * 4 + w;
  const int cand = l >> 2, sub = l & 3;
  const int ti = idx16g[q * NCAND + cand];
  const f32x4* tp = (const f32x4*)(T + (size_t)ti * DIM + sub * 128);
  const f32x4* xp = (const f32x4*)(x + (size_t)q * DIM + sub * 128);
  float dot = 0.f, tt = 0.f, xx = 0.f;
#pragma unroll
  for (int i = 0; i < 32; ++i) {
    f32x4 a = xp[i], b = tp[i];
#pragma unroll
    for (int c = 0; c < 4; ++c) {
      dot = fmaf(a[c], b[c], dot);
      tt  = fmaf(b[c], b[c], tt);
      xx  = fmaf(a[c], a[c], xx);
    }
  }
#pragma unroll
  for (int d = 1; d < 4; d <<= 1) {
    dot += __shfl_xor(dot, d, 64);
    tt  += __shfl_xor(tt, d, 64);
    xx  += __shfl_xor(xx, d, 64);
  }
  if (sub == 0) { sd2[w * NCAND + cand] = xx + tt - 2.f * dot; sti[w * NCAND + cand] = ti; }
  __syncthreads();
  if (l == 0) {
    float tv[KTOP]; int tix[KTOP];
#pragma unroll
    for (int s = 0; s < KTOP; ++s) { tv[s] = FLT_MAX; tix[s] = 0x7FFFFFFF; }
#pragma unroll
    for (int c = 0; c < NCAND; ++c) ins5(tv, tix, sd2[w * NCAND + c], sti[w * NCAND + c]);
#pragma unroll
    for (int s = 0; s < KTOP; ++s) {
      float d2 = tv[s] > 0.f ? tv[s] : 0.f;
      out[(size_t)q * KTOP + s] = sqrtf(d2);                          // topk_dists [Q,K]
      out[(size_t)NQ * KTOP + (size_t)q * KTOP + s] = (float)tix[s];  // topk_inds [Q,K]
      out[(size_t)2 * NQ * KTOP + (size_t)s * NQ + q] =
          (float)labels[tix[s]];                                       // pred [K,Q]
    }
  }
}

extern "C" void kernel_launch(void* const* d_in, const int* in_sizes, int n_in,
                              void* d_out, int out_size, void* d_ws, size_t ws_size,
                              hipStream_t stream) {
  const float* x = (const float*)d_in[0];
  const float* T = (const float*)d_in[1];
  const int* labels = (const int*)d_in[2];
  float* out = (float*)d_out;
  char* ws = (char*)d_ws;

  // ws layout (bytes), total ~128.7 MB
  float* t2     = (float*)(ws + 0);             // 400,000
  float* x2     = (float*)(ws + 401408);        // 8,192
  short* xhi    = (short*)(ws + 409600);        // 2,097,152
  short* thi    = (short*)(ws + 2506752);       // 102,498,304 (end 105,005,056)
  float* pvals  = (float*)(ws + 105005056);     // 15,728,640
  u16*   pidx16 = (u16*)(ws + 120733696);       // 7,864,320
  int*   idx16g = (int*)(ws + 128598016);       // 131,072 (end 128,729,088)

  hipMemsetAsync(ws, 0, 409600, stream);        // zero t2/x2 for atomic norms

  convert_kernel<<<CV_TBLKS + CV_XBLKS, 256, 0, stream>>>(
      x, T, xhi, thi, t2, x2);

  knn_mfma<<<QBLKS * NSUB * NCH, 256, 0, stream>>>(
      xhi, thi, t2, pvals, pidx16);

  knn_merge16<<<(NQ * 64 + 255) / 256, 256, 0, stream>>>(pvals, pidx16, idx16g);

  knn_rerank<<<NQ / 4, 256, 0, stream>>>(x, T, idx16g, labels, out);
}

// Round 8
// 665.588 us; speedup vs baseline: 1.2162x; 1.1450x over previous
//
#include <hip/hip_runtime.h>
#include <hip/hip_fp8.h>
#include <float.h>
#include <math.h>

#define NQ 2048
#define NT 100000
#define DIM 512
#define KTOP 5
#define NCAND 16            // screening survivors per query (exact re-rank set)
#define QTILE 128
#define TTILE 128
#define NTPC 13             // t-tiles per chunk
#define NCH 64              // chunk id space; 8 chunks per XCD
#define TBLKS 782           // ceil(NT/128) -> valid 128-row t-tile blocks
#define QBLKS 16            // NQ/128
#define NSUB 3              // t-sub-blocks per chunk (tiles {5,4,4})
#define CV_TBLKS (TBLKS*16) // 12512 convert tasks for T
#define CV_XBLKS ((NQ/128)*16) // 256 convert tasks for x

typedef float f32x4 __attribute__((ext_vector_type(4)));
typedef unsigned int u32;
typedef unsigned short u16;
typedef unsigned long u64;

__device__ __forceinline__ int tsub_start(int ts) { return (13 * ts + 2) / 3; }

__device__ __forceinline__ bool lt_pair(float v1, int i1, float v2, int i2) {
  return v1 < v2 || (v1 == v2 && i1 < i2);
}

// screening insert: plain < (no index tie-break; selection is value-level,
// final ordering is re-established by the exact re-rank)
__device__ __forceinline__ void ins5f(float* tv, int* tix, float sc, int idx) {
  if (sc < tv[4]) {
    tv[4] = sc; tix[4] = idx;
#pragma unroll
    for (int p = 4; p > 0; --p)
      if (tv[p] < tv[p - 1]) {
        float tf = tv[p]; tv[p] = tv[p - 1]; tv[p - 1] = tf;
        int tn = tix[p]; tix[p] = tix[p - 1]; tix[p - 1] = tn;
      }
  }
}

__device__ __forceinline__ void ins5(float* tv, int* tix, float sc, int idx) {
  if (lt_pair(sc, idx, tv[4], tix[4])) {
    tv[4] = sc; tix[4] = idx;
#pragma unroll
    for (int p = 4; p > 0; --p)
      if (lt_pair(tv[p], tix[p], tv[p - 1], tix[p - 1])) {
        float tf = tv[p]; tv[p] = tv[p - 1]; tv[p - 1] = tf;
        int tn = tix[p]; tix[p] = tix[p - 1]; tix[p - 1] = tn;
      }
  }
}

__device__ __forceinline__ void merge5(float* av, int* ai, const float* bv, const int* bi) {
  float nv[5]; int ni[5];
#pragma unroll
  for (int s = 0; s < 5; ++s) {
    if (lt_pair(av[s], ai[s], bv[4 - s], bi[4 - s])) { nv[s] = av[s]; ni[s] = ai[s]; }
    else { nv[s] = bv[4 - s]; ni[s] = bi[4 - s]; }
  }
#pragma unroll
  for (int a = 0; a < 5; ++a)
#pragma unroll
    for (int b = 0; b < 4 - a; ++b)
      if (lt_pair(nv[b + 1], ni[b + 1], nv[b], ni[b])) {
        float tf = nv[b]; nv[b] = nv[b + 1]; nv[b + 1] = tf;
        int tn = ni[b]; ni[b] = ni[b + 1]; ni[b + 1] = tn;
      }
#pragma unroll
  for (int s = 0; s < 5; ++s) { av[s] = nv[s]; ai[s] = ni[s]; }
}

// ---------------- convert: fp32 -> frag-major FP8 e4m3 (screening) ----------
// Screening error budget: e4m3 RNE dot error over 512 dims ~ +-1.8 absolute
// on d2 (std) vs ~16 gap between 5th and 16th order stats at N=100k -> ~6σ
// margin; exact fp32 re-rank of top-16 absorbs it. Since A and B fragments
// use IDENTICAL (row,k) packing, any k-permutation inside the fp8 fragment
// layout cancels in the dot product; C layout is shape-determined (verified).
__global__ __launch_bounds__(256) void convert_kernel(
    const float* __restrict__ x, const float* __restrict__ T,
    unsigned char* __restrict__ xq8, unsigned char* __restrict__ tq8,
    float* __restrict__ t2, float* __restrict__ x2) {
  __shared__ unsigned char lh[4096];   // 512 units x 8 B
  const int bid = blockIdx.x;
  const bool isT = bid < CV_TBLKS;
  const int task = isT ? bid : bid - CV_TBLKS;
  const int blk = task >> 4, kbi = task & 15;
  const float* src = isT ? T : x;
  unsigned char* dq8 = isT ? tq8 : xq8;
  float* nrm = isT ? t2 : x2;
  const int nsrc = isT ? NT : NQ;

  const int t = threadIdx.x;
  const int rr = t >> 1, half = t & 1;
  const int grow = blk * 128 + rr;
  const int rs = grow < nsrc ? grow : nsrc - 1;
  const float* p = src + (size_t)rs * DIM + kbi * 32 + half * 16;
  f32x4 v[4];
#pragma unroll
  for (int i = 0; i < 4; ++i) v[i] = ((const f32x4*)p)[i];

  float ss = 0.f;
#pragma unroll
  for (int g = 0; g < 2; ++g) {
    u64 pk = 0;
#pragma unroll
    for (int e = 0; e < 8; ++e) {
      int i = g * 8 + e;
      float f = v[i >> 2][i & 3];
      ss = fmaf(f, f, ss);
      __hip_fp8_e4m3 q8(f);            // OCP e4m3, RNE/satfinite
      pk |= (u64)__builtin_bit_cast(unsigned char, q8) << (8 * e);
    }
    // frag unit: tile = rr>>4, quad = half*2+g, m = rr&15
    int unit = (rr >> 4) * 64 + (half * 2 + g) * 16 + (rr & 15);
    *(u64*)(lh + unit * 8) = pk;
  }
  ss += __shfl_xor(ss, 1, 64);       // pair (t, t^1) share a row
  if (half == 0 && grow < nsrc) atomicAdd(nrm + grow, ss);

  __syncthreads();
  // slice = 4096 B; thread t copies bytes [t*16, t*16+16)
  size_t obase = ((size_t)(blk * 16 + kbi)) * 4096 + t * 16;
  *(f32x4*)(dq8 + obase) = *(const f32x4*)(lh + t * 16);
}

// ---------------- stage 1: screening GEMM, fp8, direct loads, swapped ops ---
// R6/R7 verdict: LDS staging loses to barrier-free direct loads (431/486 vs
// 388) -- per-kbi barrier drains cost more than the L2 bytes saved. R5 model:
// direct variants plateau at ~17.6 TB/s of L2 fragment traffic; duration
// tracks bytes. fp8 halves bytes again (8 B/lane/frag, dwordx2) at UNCHANGED
// MFMA cycle count (non-scaled fp8 = bf16 rate). Structure = R5 verbatim:
// A=T-frags (M side), B=X-frags (N side), native epilogue, no barriers.
__global__ __launch_bounds__(256, 2) void knn_mfma(
    const unsigned char* __restrict__ xq8, const unsigned char* __restrict__ tq8,
    const float* __restrict__ t2g,
    float* __restrict__ pvals, u16* __restrict__ pidx16) {
  __shared__ float msv[128 * 5];   // cross-wave (t-half) merge: 2.5 KB
  __shared__ int   msi[128 * 5];   // + 2.5 KB

  const int tid = threadIdx.x;
  const int w = tid >> 6;
  const int l = tid & 63;
  const int bid = blockIdx.x;
  const u32 rest = (u32)bid >> 3;
  const int inner = (int)(rest % 48u);
  const int chunk = (bid & 7) + 8 * (int)(rest / 48u);
  const int qblk = inner & 15;
  const int tsub = inner >> 4;                 // 0..2
  const int tstart = tsub_start(tsub);
  const int tend = tsub_start(tsub + 1);
  const int q0 = qblk * QTILE;
  const int wr = (w >> 1) * 64;    // t-offset within tile
  const int wc = (w & 1) * 64;     // q-offset within tile
  const int arow = wr >> 4;        // T fragment row group
  const int bcol = wc >> 4;        // X fragment col group

  const u64* x64 = (const u64*)xq8;
  const u64* t64 = (const u64*)tq8;

  float tv4[4][KTOP]; int tix4[4][KTOP];   // per-jj (per-q) top-5, registers
#pragma unroll
  for (int jj = 0; jj < 4; ++jj)
#pragma unroll
    for (int s = 0; s < KTOP; ++s) { tv4[jj][s] = FLT_MAX; tix4[jj][s] = 0x7FFFFFFF; }

#pragma unroll 1
  for (int tt = tstart; tt < tend; ++tt) {
    const int bblk = chunk * NTPC + tt;
    if (bblk >= TBLKS) continue;   // uniform per block: partials stay FLT_MAX
    const int tbase = bblk * TTILE;
    f32x4 acc[4][4];
#pragma unroll
    for (int i = 0; i < 4; ++i)
#pragma unroll
      for (int j = 0; j < 4; ++j) acc[i][j] = (f32x4){0.f, 0.f, 0.f, 0.f};

    // element offsets (u64 units); kbi stride = 512 units (4096 B)
    u32 offA = (u32)(bblk * 16) * 512u + (u32)(arow * 64 + l);  // T (M side)
    u32 offB = (u32)(qblk * 16) * 512u + (u32)(bcol * 64 + l);  // X (N side)
    long ah[4], bh[4];
#pragma unroll 1
    for (int kbi = 0; kbi < 16; ++kbi) {
#pragma unroll
      for (int i = 0; i < 4; ++i) {
        ah[i] = (long)t64[offA + i * 64];
        bh[i] = (long)x64[offB + i * 64];
      }
      offA += 512; offB += 512;
      __builtin_amdgcn_s_setprio(1);
#pragma unroll
      for (int j = 0; j < 4; ++j)
#pragma unroll
        for (int i = 0; i < 4; ++i)
          acc[i][j] = __builtin_amdgcn_mfma_f32_16x16x32_fp8_fp8(ah[i], bh[j], acc[i][j], 0, 0, 0);
      __builtin_amdgcn_s_setprio(0);
    }

    // epilogue, native layout: lane owns q = wc+jj*16+(l&15); t varies by (i,r)
    const int tg0 = tbase + wr + ((l >> 4) << 2);
    float t2v[16];
#pragma unroll
    for (int i = 0; i < 4; ++i)
#pragma unroll
      for (int r = 0; r < 4; ++r) {
        int t = tg0 + i * 16 + r;
        float vv = t2g[t < NT ? t : NT - 1];
        t2v[i * 4 + r] = t < NT ? vv : FLT_MAX;   // FLT_MAX-2acc rounds to FLT_MAX
      }
#pragma unroll
    for (int jj = 0; jj < 4; ++jj)
#pragma unroll
      for (int i = 0; i < 4; ++i)
#pragma unroll
        for (int r = 0; r < 4; ++r) {
          float sc = fmaf(-2.f, acc[i][jj][r], t2v[i * 4 + r]);
          ins5f(tv4[jj], tix4[jj], sc, tg0 + i * 16 + r);
        }
  }

  // merge the 4 lanes sharing (l&15, jj): butterfly xor 16, 32 (once per block)
#pragma unroll
  for (int jj = 0; jj < 4; ++jj)
#pragma unroll
    for (int d = 16; d <= 32; d <<= 1) {
      float ov[KTOP]; int oi[KTOP];
#pragma unroll
      for (int s = 0; s < KTOP; ++s) {
        ov[s] = __shfl_xor(tv4[jj][s], d, 64);
        oi[s] = __shfl_xor(tix4[jj][s], d, 64);
      }
      merge5(tv4[jj], tix4[jj], ov, oi);
    }

  // cross-wave: waves 2,3 (t-half 1) publish, waves 0,1 consume + write out
  const int blockBase = (chunk * NTPC + tstart) * TTILE;
  if ((w >> 1) && (l >> 4) == 0) {
#pragma unroll
    for (int jj = 0; jj < 4; ++jj) {
      int qr = wc + jj * 16 + l;
#pragma unroll
      for (int s = 0; s < KTOP; ++s) {
        msv[qr * 5 + s] = tv4[jj][s];
        msi[qr * 5 + s] = tix4[jj][s];
      }
    }
  }
  __syncthreads();
  if (!(w >> 1) && (l >> 4) == 0) {
#pragma unroll
    for (int jj = 0; jj < 4; ++jj) {
      int qr = wc + jj * 16 + l;
      float ov[KTOP]; int oi[KTOP];
#pragma unroll
      for (int s = 0; s < KTOP; ++s) { ov[s] = msv[qr * 5 + s]; oi[s] = msi[qr * 5 + s]; }
      merge5(tv4[jj], tix4[jj], ov, oi);
      int q = q0 + qr;
      // u16 local index: block covers <=5 tiles = 640 t's from blockBase.
      // FLT_MAX sentinels carry garbage offsets - value-masked, never selected.
      size_t base = ((size_t)q * (NCH * NSUB) + (chunk * NSUB + tsub)) * KTOP;
#pragma unroll
      for (int s = 0; s < KTOP; ++s) {
        pvals[base + s] = tv4[jj][s];
        pidx16[base + s] = (u16)(tix4[jj][s] - blockBase);
      }
    }
  }
}

// ---------------- merge16: 960 approx partials -> top-16 indices/query ------
// One wave per query. 16 rounds of global argmin via butterfly reduce; the
// owning lane masks the winner. All register arrays statically indexed.
__global__ __launch_bounds__(256) void knn_merge16(
    const float* __restrict__ pvals, const u16* __restrict__ pidx16,
    int* __restrict__ idx16g) {
  const int M = NCH * NSUB * KTOP;  // 960 = 64 lanes x 15
  int q = (blockIdx.x * 256 + threadIdx.x) >> 6;
  int l = threadIdx.x & 63;
  if (q >= NQ) return;
  float v[15]; int ix[15];
  size_t base = (size_t)q * M;
#pragma unroll
  for (int j = 0; j < 15; ++j) {
    int m = j * 64 + l;
    int slot = m / KTOP;                    // candidate slot = chunk*NSUB+tsub
    int ch = slot / NSUB, ts = slot % NSUB;
    int gb = (ch * NTPC + tsub_start(ts)) * TTILE;
    v[j] = pvals[base + m];
    ix[j] = gb + (int)pidx16[base + m];
  }
  int mywin = 0x7FFFFFFF;
#pragma unroll 1
  for (int r = 0; r < NCAND; ++r) {
    float bv = FLT_MAX; int bi = 0x7FFFFFFF;
#pragma unroll
    for (int j = 0; j < 15; ++j)
      if (lt_pair(v[j], ix[j], bv, bi)) { bv = v[j]; bi = ix[j]; }
#pragma unroll
    for (int d = 1; d < 64; d <<= 1) {
      float ov = __shfl_xor(bv, d, 64);
      int oi = __shfl_xor(bi, d, 64);
      if (lt_pair(ov, oi, bv, bi)) { bv = ov; bi = oi; }
    }
    if (l == r) mywin = bi;     // all lanes agree on bi; lane r records it
#pragma unroll
    for (int j = 0; j < 15; ++j)
      if (ix[j] == bi) v[j] = FLT_MAX;      // global idx unique -> safe mask
  }
  if (l < NCAND) idx16g[q * NCAND + l] = mywin;
}

// ---------------- rerank: exact fp32 d2 for 16 cands/query -> final top-5 ---
__global__ __launch_bounds__(256) void knn_rerank(
    const float* __restrict__ x, const float* __restrict__ T,
    const int* __restrict__ idx16g, const int* __restrict__ labels,
    float* __restrict__ out) {
  __shared__ float sd2[4 * NCAND];
  __shared__ int sti[4 * NCAND];
  const int w = threadIdx.x >> 6, l = threadIdx.x & 63;
  const int q = blockIdx.x * 4 + w;
  const int cand = l >> 2, sub = l & 3;
  const int ti = idx16g[q * NCAND + cand];
  const f32x4* tp = (const f32x4*)(T + (size_t)ti * DIM + sub * 128);
  const f32x4* xp = (const f32x4*)(x + (size_t)q * DIM + sub * 128);
  float dot = 0.f, tt = 0.f, xx = 0.f;
#pragma unroll
  for (int i = 0; i < 32; ++i) {
    f32x4 a = xp[i], b = tp[i];
#pragma unroll
    for (int c = 0; c < 4; ++c) {
      dot = fmaf(a[c], b[c], dot);
      tt  = fmaf(b[c], b[c], tt);
      xx  = fmaf(a[c], a[c], xx);
    }
  }
#pragma unroll
  for (int d = 1; d < 4; d <<= 1) {
    dot += __shfl_xor(dot, d, 64);
    tt  += __shfl_xor(tt, d, 64);
    xx  += __shfl_xor(xx, d, 64);
  }
  if (sub == 0) { sd2[w * NCAND + cand] = xx + tt - 2.f * dot; sti[w * NCAND + cand] = ti; }
  __syncthreads();
  if (l == 0) {
    float tv[KTOP]; int tix[KTOP];
#pragma unroll
    for (int s = 0; s < KTOP; ++s) { tv[s] = FLT_MAX; tix[s] = 0x7FFFFFFF; }
#pragma unroll
    for (int c = 0; c < NCAND; ++c) ins5(tv, tix, sd2[w * NCAND + c], sti[w * NCAND + c]);
#pragma unroll
    for (int s = 0; s < KTOP; ++s) {
      float d2 = tv[s] > 0.f ? tv[s] : 0.f;
      out[(size_t)q * KTOP + s] = sqrtf(d2);                          // topk_dists [Q,K]
      out[(size_t)NQ * KTOP + (size_t)q * KTOP + s] = (float)tix[s];  // topk_inds [Q,K]
      out[(size_t)2 * NQ * KTOP + (size_t)s * NQ + q] =
          (float)labels[tix[s]];                                       // pred [K,Q]
    }
  }
}

extern "C" void kernel_launch(void* const* d_in, const int* in_sizes, int n_in,
                              void* d_out, int out_size, void* d_ws, size_t ws_size,
                              hipStream_t stream) {
  const float* x = (const float*)d_in[0];
  const float* T = (const float*)d_in[1];
  const int* labels = (const int*)d_in[2];
  float* out = (float*)d_out;
  char* ws = (char*)d_ws;

  // ws layout (bytes), total ~64.6 MB (fp8 fragment arrays halve the footprint)
  float* t2     = (float*)(ws + 0);             // 400,000
  float* x2     = (float*)(ws + 401408);        // 8,192
  unsigned char* xq8 = (unsigned char*)(ws + 409600);    // 1,048,576
  unsigned char* tq8 = (unsigned char*)(ws + 1458176);   // 51,249,152 (end 52,707,328)
  float* pvals  = (float*)(ws + 52707328);      // 7,864,320
  u16*   pidx16 = (u16*)(ws + 60571648);        // 3,932,160
  int*   idx16g = (int*)(ws + 64503808);        // 131,072 (end 64,634,880)

  hipMemsetAsync(ws, 0, 409600, stream);        // zero t2/x2 for atomic norms

  convert_kernel<<<CV_TBLKS + CV_XBLKS, 256, 0, stream>>>(
      x, T, xq8, tq8, t2, x2);

  knn_mfma<<<QBLKS * NSUB * NCH, 256, 0, stream>>>(
      xq8, tq8, t2, pvals, pidx16);

  knn_merge16<<<(NQ * 64 + 255) / 256, 256, 0, stream>>>(pvals, pidx16, idx16g);

  knn_rerank<<<NQ / 4, 256, 0, stream>>>(x, T, idx16g, labels, out);
}

// Round 10
// 609.475 us; speedup vs baseline: 1.3281x; 1.0921x over previous
//
#include <hip/hip_runtime.h>
#include <hip/hip_fp8.h>
#include <float.h>
#include <math.h>

#define NQ 2048
#define NT 100000
#define DIM 512
#define KTOP 5
#define NCAND 16            // screening survivors per query (exact re-rank set)
#define QTILE 128
#define TTILE 128
#define NTPC 13             // t-tiles per chunk
#define NCH 64              // chunk id space; 8 chunks per XCD
#define TBLKS 782           // ceil(NT/128) -> valid 128-row t-tile blocks
#define QBLKS 16            // NQ/128
#define NSUB 3              // t-sub-blocks per chunk (tiles {5,4,4})
#define CVP_TBLKS (TBLKS*8) // 6256 paired convert tasks for T (64-col pairs)
#define CVP_XBLKS (QBLKS*8) // 128 paired convert tasks for x

typedef float f32x4 __attribute__((ext_vector_type(4)));
typedef long lg2 __attribute__((ext_vector_type(2)));
typedef unsigned int u32;
typedef unsigned short u16;
typedef unsigned long u64;

__device__ __forceinline__ int tsub_start(int ts) { return (13 * ts + 2) / 3; }

__device__ __forceinline__ bool lt_pair(float v1, int i1, float v2, int i2) {
  return v1 < v2 || (v1 == v2 && i1 < i2);
}

// screening insert: plain < (no index tie-break; selection is value-level,
// final ordering is re-established by the exact re-rank)
__device__ __forceinline__ void ins5f(float* tv, int* tix, float sc, int idx) {
  if (sc < tv[4]) {
    tv[4] = sc; tix[4] = idx;
#pragma unroll
    for (int p = 4; p > 0; --p)
      if (tv[p] < tv[p - 1]) {
        float tf = tv[p]; tv[p] = tv[p - 1]; tv[p - 1] = tf;
        int tn = tix[p]; tix[p] = tix[p - 1]; tix[p - 1] = tn;
      }
  }
}

__device__ __forceinline__ void ins5(float* tv, int* tix, float sc, int idx) {
  if (lt_pair(sc, idx, tv[4], tix[4])) {
    tv[4] = sc; tix[4] = idx;
#pragma unroll
    for (int p = 4; p > 0; --p)
      if (lt_pair(tv[p], tix[p], tv[p - 1], tix[p - 1])) {
        float tf = tv[p]; tv[p] = tv[p - 1]; tv[p - 1] = tf;
        int tn = tix[p]; tix[p] = tix[p - 1]; tix[p - 1] = tn;
      }
  }
}

__device__ __forceinline__ void merge5(float* av, int* ai, const float* bv, const int* bi) {
  float nv[5]; int ni[5];
#pragma unroll
  for (int s = 0; s < 5; ++s) {
    if (lt_pair(av[s], ai[s], bv[4 - s], bi[4 - s])) { nv[s] = av[s]; ni[s] = ai[s]; }
    else { nv[s] = bv[4 - s]; ni[s] = bi[4 - s]; }
  }
#pragma unroll
  for (int a = 0; a < 5; ++a)
#pragma unroll
    for (int b = 0; b < 4 - a; ++b)
      if (lt_pair(nv[b + 1], ni[b + 1], nv[b], ni[b])) {
        float tf = nv[b]; nv[b] = nv[b + 1]; nv[b + 1] = tf;
        int tn = ni[b]; ni[b] = ni[b + 1]; ni[b + 1] = tn;
      }
#pragma unroll
  for (int s = 0; s < 5; ++s) { av[s] = nv[s]; ai[s] = ni[s]; }
}

// ---------------- convert: fp32 -> PAIRED frag-major FP8 e4m3 ---------------
// kbi-PAIR layout: paired slice (blk,pair) = 512 units x 16 B = 8192 B DENSE
// (R9 bug: 16384-B stride with half-empty slices overflowed the 51.2 MB
// buffer and trampled pvals -> absmax 61416. Fixed: dense 8192-B stride.)
// Unit u (tile*64+quad*16+m) holds [kbi-even 8B | kbi-odd 8B]; one dwordx4 in
// stage 1 delivers TWO kbi fragments -> halves the VMEM instruction count
// (R8 law: duration ~ 125 cyc per wave-load instruction, width-independent).
__global__ __launch_bounds__(256) void convert_kernel(
    const float* __restrict__ x, const float* __restrict__ T,
    unsigned char* __restrict__ xq8, unsigned char* __restrict__ tq8,
    float* __restrict__ t2, float* __restrict__ x2) {
  __shared__ unsigned char lh[8192];
  const int bid = blockIdx.x;
  const bool isT = bid < CVP_TBLKS;
  const int task = isT ? bid : bid - CVP_TBLKS;
  const int blk = task >> 3, pair = task & 7;
  const float* src = isT ? T : x;
  unsigned char* dq8 = isT ? tq8 : xq8;
  float* nrm = isT ? t2 : x2;
  const int nsrc = isT ? NT : NQ;

  const int t = threadIdx.x;
  const int rr = t >> 1, half = t & 1;   // half = kbi parity within the pair
  const int grow = blk * 128 + rr;
  const int rs = grow < nsrc ? grow : nsrc - 1;
  const float* p = src + (size_t)rs * DIM + pair * 64 + half * 32;
  f32x4 v[8];
#pragma unroll
  for (int i = 0; i < 8; ++i) v[i] = ((const f32x4*)p)[i];

  float ss = 0.f;
#pragma unroll
  for (int g = 0; g < 4; ++g) {          // quad g within the 32-col k-window
    u64 pk = 0;
#pragma unroll
    for (int e = 0; e < 8; ++e) {
      int i = g * 8 + e;
      float f = v[i >> 2][i & 3];
      ss = fmaf(f, f, ss);
      __hip_fp8_e4m3 q8(f);              // OCP e4m3, RNE/satfinite
      pk |= (u64)__builtin_bit_cast(unsigned char, q8) << (8 * e);
    }
    int unit = (rr >> 4) * 64 + g * 16 + (rr & 15);
    *(u64*)(lh + unit * 16 + half * 8) = pk;
  }
  ss += __shfl_xor(ss, 1, 64);           // pair (t, t^1) share a row (64 cols)
  if (half == 0 && grow < nsrc) atomicAdd(nrm + grow, ss);

  __syncthreads();
  // dense paired slice = 8192 B; thread t copies bytes [t*32, t*32+32)
  size_t obase = ((size_t)(blk * 8 + pair)) * 8192 + t * 32;
  *(f32x4*)(dq8 + obase)      = *(const f32x4*)(lh + t * 32);
  *(f32x4*)(dq8 + obase + 16) = *(const f32x4*)(lh + t * 32 + 16);
}

// ---------------- stage 1: screening GEMM, fp8, kbi-paired dwordx4 loads ----
// R8 post-mortem law: stage-1 duration ~ #vector-load instructions (125 cyc
// per wave-load, WIDTH-INDEPENDENT; bytes at constant instrs ~ free). So:
// dwordx4 per fragment-pair -> 64 loads/tile instead of 128, same bytes, same
// 256 MFMA/tile. (256,2) kept: the VMEM front-end is CU-shared (R3: 3 waves
// ~nil), so instruction count is the only lever. Structure otherwise = R8:
// swapped operands (A=T rows, B=X cols), native epilogue, barrier-free.
__global__ __launch_bounds__(256, 2) void knn_mfma(
    const unsigned char* __restrict__ xq8, const unsigned char* __restrict__ tq8,
    const float* __restrict__ t2g,
    float* __restrict__ pvals, u16* __restrict__ pidx16) {
  __shared__ float msv[128 * 5];   // cross-wave (t-half) merge: 2.5 KB
  __shared__ int   msi[128 * 5];   // + 2.5 KB

  const int tid = threadIdx.x;
  const int w = tid >> 6;
  const int l = tid & 63;
  const int bid = blockIdx.x;
  const u32 rest = (u32)bid >> 3;
  const int inner = (int)(rest % 48u);
  const int chunk = (bid & 7) + 8 * (int)(rest / 48u);
  const int qblk = inner & 15;
  const int tsub = inner >> 4;                 // 0..2
  const int tstart = tsub_start(tsub);
  const int tend = tsub_start(tsub + 1);
  const int q0 = qblk * QTILE;
  const int wr = (w >> 1) * 64;    // t-offset within tile
  const int wc = (w & 1) * 64;     // q-offset within tile
  const int arow = wr >> 4;        // T fragment row group
  const int bcol = wc >> 4;        // X fragment col group

  const f32x4* x16 = (const f32x4*)xq8;   // 16-B units (kbi pairs)
  const f32x4* t16 = (const f32x4*)tq8;

  float tv4[4][KTOP]; int tix4[4][KTOP];   // per-jj (per-q) top-5, registers
#pragma unroll
  for (int jj = 0; jj < 4; ++jj)
#pragma unroll
    for (int s = 0; s < KTOP; ++s) { tv4[jj][s] = FLT_MAX; tix4[jj][s] = 0x7FFFFFFF; }

#pragma unroll 1
  for (int tt = tstart; tt < tend; ++tt) {
    const int bblk = chunk * NTPC + tt;
    if (bblk >= TBLKS) continue;   // uniform per block: partials stay FLT_MAX
    const int tbase = bblk * TTILE;
    f32x4 acc[4][4];
#pragma unroll
    for (int i = 0; i < 4; ++i)
#pragma unroll
      for (int j = 0; j < 4; ++j) acc[i][j] = (f32x4){0.f, 0.f, 0.f, 0.f};

    // element offsets (16-B units); dense paired slice = 512 units (8192 B)
    u32 offA = (u32)(bblk * 8) * 512u + (u32)(arow * 64 + l);  // T (M side)
    u32 offB = (u32)(qblk * 8) * 512u + (u32)(bcol * 64 + l);  // X (N side)
#pragma unroll 1
    for (int p = 0; p < 8; ++p) {          // 8 kbi-pairs
      f32x4 a2[4], b2[4];
#pragma unroll
      for (int i = 0; i < 4; ++i) {
        a2[i] = t16[offA + i * 64];
        b2[i] = x16[offB + i * 64];
      }
      offA += 512; offB += 512;
      __builtin_amdgcn_s_setprio(1);
#pragma unroll
      for (int j = 0; j < 4; ++j) {
        const lg2 bb = __builtin_bit_cast(lg2, b2[j]);
#pragma unroll
        for (int i = 0; i < 4; ++i) {
          const lg2 aa = __builtin_bit_cast(lg2, a2[i]);
          acc[i][j] = __builtin_amdgcn_mfma_f32_16x16x32_fp8_fp8(aa[0], bb[0], acc[i][j], 0, 0, 0);
          acc[i][j] = __builtin_amdgcn_mfma_f32_16x16x32_fp8_fp8(aa[1], bb[1], acc[i][j], 0, 0, 0);
        }
      }
      __builtin_amdgcn_s_setprio(0);
    }

    // epilogue, native layout: lane owns q = wc+jj*16+(l&15); t varies by (i,r)
    const int tg0 = tbase + wr + ((l >> 4) << 2);
    float t2v[16];
#pragma unroll
    for (int i = 0; i < 4; ++i)
#pragma unroll
      for (int r = 0; r < 4; ++r) {
        int t = tg0 + i * 16 + r;
        float vv = t2g[t < NT ? t : NT - 1];
        t2v[i * 4 + r] = t < NT ? vv : FLT_MAX;   // FLT_MAX-2acc rounds to FLT_MAX
      }
#pragma unroll
    for (int jj = 0; jj < 4; ++jj)
#pragma unroll
      for (int i = 0; i < 4; ++i)
#pragma unroll
        for (int r = 0; r < 4; ++r) {
          float sc = fmaf(-2.f, acc[i][jj][r], t2v[i * 4 + r]);
          ins5f(tv4[jj], tix4[jj], sc, tg0 + i * 16 + r);
        }
  }

  // merge the 4 lanes sharing (l&15, jj): butterfly xor 16, 32 (once per block)
#pragma unroll
  for (int jj = 0; jj < 4; ++jj)
#pragma unroll
    for (int d = 16; d <= 32; d <<= 1) {
      float ov[KTOP]; int oi[KTOP];
#pragma unroll
      for (int s = 0; s < KTOP; ++s) {
        ov[s] = __shfl_xor(tv4[jj][s], d, 64);
        oi[s] = __shfl_xor(tix4[jj][s], d, 64);
      }
      merge5(tv4[jj], tix4[jj], ov, oi);
    }

  // cross-wave: waves 2,3 (t-half 1) publish, waves 0,1 consume + write out
  const int blockBase = (chunk * NTPC + tstart) * TTILE;
  if ((w >> 1) && (l >> 4) == 0) {
#pragma unroll
    for (int jj = 0; jj < 4; ++jj) {
      int qr = wc + jj * 16 + l;
#pragma unroll
      for (int s = 0; s < KTOP; ++s) {
        msv[qr * 5 + s] = tv4[jj][s];
        msi[qr * 5 + s] = tix4[jj][s];
      }
    }
  }
  __syncthreads();
  if (!(w >> 1) && (l >> 4) == 0) {
#pragma unroll
    for (int jj = 0; jj < 4; ++jj) {
      int qr = wc + jj * 16 + l;
      float ov[KTOP]; int oi[KTOP];
#pragma unroll
      for (int s = 0; s < KTOP; ++s) { ov[s] = msv[qr * 5 + s]; oi[s] = msi[qr * 5 + s]; }
      merge5(tv4[jj], tix4[jj], ov, oi);
      int q = q0 + qr;
      // u16 local index: block covers <=5 tiles = 640 t's from blockBase.
      // FLT_MAX sentinels carry garbage offsets - value-masked, never selected.
      size_t base = ((size_t)q * (NCH * NSUB) + (chunk * NSUB + tsub)) * KTOP;
#pragma unroll
      for (int s = 0; s < KTOP; ++s) {
        pvals[base + s] = tv4[jj][s];
        pidx16[base + s] = (u16)(tix4[jj][s] - blockBase);
      }
    }
  }
}

// ---------------- merge16: 960 approx partials -> top-16 indices/query ------
// One wave per query. 16 rounds of global argmin via butterfly reduce; the
// owning lane masks the winner. All register arrays statically indexed.
__global__ __launch_bounds__(256) void knn_merge16(
    const float* __restrict__ pvals, const u16* __restrict__ pidx16,
    int* __restrict__ idx16g) {
  const int M = NCH * NSUB * KTOP;  // 960 = 64 lanes x 15
  int q = (blockIdx.x * 256 + threadIdx.x) >> 6;
  int l = threadIdx.x & 63;
  if (q >= NQ) return;
  float v[15]; int ix[15];
  size_t base = (size_t)q * M;
#pragma unroll
  for (int j = 0; j < 15; ++j) {
    int m = j * 64 + l;
    int slot = m / KTOP;                    // candidate slot = chunk*NSUB+tsub
    int ch = slot / NSUB, ts = slot % NSUB;
    int gb = (ch * NTPC + tsub_start(ts)) * TTILE;
    v[j] = pvals[base + m];
    ix[j] = gb + (int)pidx16[base + m];
  }
  int mywin = 0x7FFFFFFF;
#pragma unroll 1
  for (int r = 0; r < NCAND; ++r) {
    float bv = FLT_MAX; int bi = 0x7FFFFFFF;
#pragma unroll
    for (int j = 0; j < 15; ++j)
      if (lt_pair(v[j], ix[j], bv, bi)) { bv = v[j]; bi = ix[j]; }
#pragma unroll
    for (int d = 1; d < 64; d <<= 1) {
      float ov = __shfl_xor(bv, d, 64);
      int oi = __shfl_xor(bi, d, 64);
      if (lt_pair(ov, oi, bv, bi)) { bv = ov; bi = oi; }
    }
    if (l == r) mywin = bi;     // all lanes agree on bi; lane r records it
#pragma unroll
    for (int j = 0; j < 15; ++j)
      if (ix[j] == bi) v[j] = FLT_MAX;      // global idx unique -> safe mask
  }
  if (l < NCAND) idx16g[q * NCAND + l] = mywin;
}

// ---------------- rerank: exact fp32 d2 for 16 cands/query -> final top-5 ---
__global__ __launch_bounds__(256) void knn_rerank(
    const float* __restrict__ x, const float* __restrict__ T,
    const int* __restrict__ idx16g, const int* __restrict__ labels,
    float* __restrict__ out) {
  __shared__ float sd2[4 * NCAND];
  __shared__ int sti[4 * NCAND];
  const int w = threadIdx.x >> 6, l = threadIdx.x & 63;
  const int q = blockIdx.x * 4 + w;
  const int cand = l >> 2, sub = l & 3;
  const int ti = idx16g[q * NCAND + cand];
  const f32x4* tp = (const f32x4*)(T + (size_t)ti * DIM + sub * 128);
  const f32x4* xp = (const f32x4*)(x + (size_t)q * DIM + sub * 128);
  float dot = 0.f, tt = 0.f, xx = 0.f;
#pragma unroll
  for (int i = 0; i < 32; ++i) {
    f32x4 a = xp[i], b = tp[i];
#pragma unroll
    for (int c = 0; c < 4; ++c) {
      dot = fmaf(a[c], b[c], dot);
      tt  = fmaf(b[c], b[c], tt);
      xx  = fmaf(a[c], a[c], xx);
    }
  }
#pragma unroll
  for (int d = 1; d < 4; d <<= 1) {
    dot += __shfl_xor(dot, d, 64);
    tt  += __shfl_xor(tt, d, 64);
    xx  += __shfl_xor(xx, d, 64);
  }
  if (sub == 0) { sd2[w * NCAND + cand] = xx + tt - 2.f * dot; sti[w * NCAND + cand] = ti; }
  __syncthreads();
  if (l == 0) {
    float tv[KTOP]; int tix[KTOP];
#pragma unroll
    for (int s = 0; s < KTOP; ++s) { tv[s] = FLT_MAX; tix[s] = 0x7FFFFFFF; }
#pragma unroll
    for (int c = 0; c < NCAND; ++c) ins5(tv, tix, sd2[w * NCAND + c], sti[w * NCAND + c]);
#pragma unroll
    for (int s = 0; s < KTOP; ++s) {
      float d2 = tv[s] > 0.f ? tv[s] : 0.f;
      out[(size_t)q * KTOP + s] = sqrtf(d2);                          // topk_dists [Q,K]
      out[(size_t)NQ * KTOP + (size_t)q * KTOP + s] = (float)tix[s];  // topk_inds [Q,K]
      out[(size_t)2 * NQ * KTOP + (size_t)s * NQ + q] =
          (float)labels[tix[s]];                                       // pred [K,Q]
    }
  }
}

extern "C" void kernel_launch(void* const* d_in, const int* in_sizes, int n_in,
                              void* d_out, int out_size, void* d_ws, size_t ws_size,
                              hipStream_t stream) {
  const float* x = (const float*)d_in[0];
  const float* T = (const float*)d_in[1];
  const int* labels = (const int*)d_in[2];
  float* out = (float*)d_out;
  char* ws = (char*)d_ws;

  // ws layout (bytes), total ~64.6 MB
  float* t2     = (float*)(ws + 0);             // 400,000
  float* x2     = (float*)(ws + 401408);        // 8,192
  unsigned char* xq8 = (unsigned char*)(ws + 409600);    // 1,048,576 = 16*8*8192
  unsigned char* tq8 = (unsigned char*)(ws + 1458176);   // 51,249,152 = 782*8*8192 (end 52,707,328)
  float* pvals  = (float*)(ws + 52707328);      // 7,864,320
  u16*   pidx16 = (u16*)(ws + 60571648);        // 3,932,160
  int*   idx16g = (int*)(ws + 64503808);        // 131,072 (end 64,634,880)

  hipMemsetAsync(ws, 0, 409600, stream);        // zero t2/x2 for atomic norms

  convert_kernel<<<CVP_TBLKS + CVP_XBLKS, 256, 0, stream>>>(
      x, T, xq8, tq8, t2, x2);

  knn_mfma<<<QBLKS * NSUB * NCH, 256, 0, stream>>>(
      xq8, tq8, t2, pvals, pidx16);

  knn_merge16<<<(NQ * 64 + 255) / 256, 256, 0, stream>>>(pvals, pidx16, idx16g);

  knn_rerank<<<NQ / 4, 256, 0, stream>>>(x, T, idx16g, labels, out);
}